// Round 1
// baseline (433.229 us; speedup 1.0000x reference)
//
#include <hip/hip_runtime.h>

// 2D Haar DWT: x (16,64,256,256) f32 -> (ll, lh, hl, hh) each (16,64,128,128) f32,
// concatenated flat in d_out. Each output element is a +/- butterfly over a 2x2
// input block scaled by 1/2 (applied as two r=1/sqrt(2) stages to match the
// reference's two sequential f32 matmuls' rounding).

constexpr int BC = 16 * 64;   // flattened batch*channel
constexpr int H  = 256, W  = 256;
constexpr int Ho = 128, Wo = 128;

__global__ __launch_bounds__(256) void dwt_haar_kernel(const float* __restrict__ x,
                                                       float* __restrict__ out) {
    const unsigned int tid = blockIdx.x * blockDim.x + threadIdx.x;
    const unsigned int jw = tid & 63u;           // float4 index along row: cols 4jw..4jw+3
    const unsigned int i  = (tid >> 6) & 127u;   // output row
    const unsigned int bc = tid >> 13;           // 0..1023

    const float r = 0.70710678118654752440f;     // rounds to f32(1/sqrt(2))

    const size_t xbase = (size_t)bc * (H * W) + (size_t)(2u * i) * W + 4u * jw;
    const float4 a = *(const float4*)(x + xbase);        // row 2i
    const float4 b = *(const float4*)(x + xbase + W);    // row 2i+1

    // row transform (low/high) at the 4 input columns
    const float l0 = r * (a.x + b.x), l1 = r * (a.y + b.y);
    const float l2 = r * (a.z + b.z), l3 = r * (a.w + b.w);
    const float h0 = r * (a.x - b.x), h1 = r * (a.y - b.y);
    const float h2 = r * (a.z - b.z), h3 = r * (a.w - b.w);

    // column transform -> 2 output columns per band
    const float2 ll = make_float2(r * (l0 + l1), r * (l2 + l3));
    const float2 lh = make_float2(r * (l0 - l1), r * (l2 - l3));
    const float2 hl = make_float2(r * (h0 + h1), r * (h2 + h3));
    const float2 hh = make_float2(r * (h0 - h1), r * (h2 - h3));

    const size_t band  = (size_t)BC * Ho * Wo;   // 16,777,216 elements per band
    const size_t obase = (size_t)bc * (Ho * Wo) + (size_t)i * Wo + 2u * jw;

    *(float2*)(out + obase)            = ll;
    *(float2*)(out + band + obase)     = lh;
    *(float2*)(out + 2 * band + obase) = hl;
    *(float2*)(out + 3 * band + obase) = hh;
}

extern "C" void kernel_launch(void* const* d_in, const int* in_sizes, int n_in,
                              void* d_out, int out_size, void* d_ws, size_t ws_size,
                              hipStream_t stream) {
    const float* x = (const float*)d_in[0];
    float* out = (float*)d_out;

    const int total_threads = BC * Ho * (Wo / 2);   // 8,388,608
    const int block = 256;
    const int grid = total_threads / block;          // 32,768

    dwt_haar_kernel<<<grid, block, 0, stream>>>(x, out);
}

// Round 3
// 418.008 us; speedup vs baseline: 1.0364x; 1.0364x over previous
//
#include <hip/hip_runtime.h>

// 2D Haar DWT: x (16,64,256,256) f32 -> (ll, lh, hl, hh) each (16,64,128,128) f32,
// concatenated flat in d_out. Each output element is a +/- butterfly over a 2x2
// input block, applied as two r=1/sqrt(2) stages to match the reference's two
// sequential f32 matmuls' rounding.
//
// R2: non-temporal loads/stores (268 MB read + 268 MB written, each touched
// once -> don't thrash L2/L3 with dead lines). Uses clang ext_vector_type
// because __builtin_nontemporal_* rejects HIP_vector_type classes.

constexpr int BC = 16 * 64;   // flattened batch*channel
constexpr int H  = 256, W  = 256;
constexpr int Ho = 128, Wo = 128;

typedef float v4f __attribute__((ext_vector_type(4)));
typedef float v2f __attribute__((ext_vector_type(2)));

__global__ __launch_bounds__(256) void dwt_haar_kernel(const float* __restrict__ x,
                                                       float* __restrict__ out) {
    const unsigned int tid = blockIdx.x * blockDim.x + threadIdx.x;
    const unsigned int jw = tid & 63u;           // float4 index along row: cols 4jw..4jw+3
    const unsigned int i  = (tid >> 6) & 127u;   // output row
    const unsigned int bc = tid >> 13;           // 0..1023

    const float r = 0.70710678118654752440f;     // rounds to f32(1/sqrt(2))

    const size_t xbase = (size_t)bc * (H * W) + (size_t)(2u * i) * W + 4u * jw;
    const v4f a = __builtin_nontemporal_load((const v4f*)(x + xbase));      // row 2i
    const v4f b = __builtin_nontemporal_load((const v4f*)(x + xbase + W));  // row 2i+1

    // row transform (low/high) at the 4 input columns
    const float l0 = r * (a.x + b.x), l1 = r * (a.y + b.y);
    const float l2 = r * (a.z + b.z), l3 = r * (a.w + b.w);
    const float h0 = r * (a.x - b.x), h1 = r * (a.y - b.y);
    const float h2 = r * (a.z - b.z), h3 = r * (a.w - b.w);

    // column transform -> 2 output columns per band
    const v2f ll = {r * (l0 + l1), r * (l2 + l3)};
    const v2f lh = {r * (l0 - l1), r * (l2 - l3)};
    const v2f hl = {r * (h0 + h1), r * (h2 + h3)};
    const v2f hh = {r * (h0 - h1), r * (h2 - h3)};

    const size_t band  = (size_t)BC * Ho * Wo;   // 16,777,216 elements per band
    const size_t obase = (size_t)bc * (Ho * Wo) + (size_t)i * Wo + 2u * jw;

    __builtin_nontemporal_store(ll, (v2f*)(out + obase));
    __builtin_nontemporal_store(lh, (v2f*)(out + band + obase));
    __builtin_nontemporal_store(hl, (v2f*)(out + 2 * band + obase));
    __builtin_nontemporal_store(hh, (v2f*)(out + 3 * band + obase));
}

extern "C" void kernel_launch(void* const* d_in, const int* in_sizes, int n_in,
                              void* d_out, int out_size, void* d_ws, size_t ws_size,
                              hipStream_t stream) {
    const float* x = (const float*)d_in[0];
    float* out = (float*)d_out;

    const int total_threads = BC * Ho * (Wo / 2);   // 8,388,608
    const int block = 256;
    const int grid = total_threads / block;          // 32,768

    dwt_haar_kernel<<<grid, block, 0, stream>>>(x, out);
}